// Round 4
// baseline (593.759 us; speedup 1.0000x reference)
//
#include <hip/hip_runtime.h>
#include <hip/hip_bf16.h>

// Fused LSTM (T=512, B=512, IN=300, H=16) + MLP head, fp32 in/out.
// ONE kernel, one wave per batch (512 blocks x 64 threads).
// Per 16-step chunk, software-pipelined in a single wave:
//   1. issue chunk c+1's x-loads (20 dwordx4, in flight across the scan)
//   2. write chunk c's MFMA acc (+bias) -> xs LDS (pad 17, conflict-free)
//   3. scan 16 steps (lane = gate-row qd*16+j; h wave-uniform via readlane)
//   4. MFMA chunk c+1 (bf16 16x16x32, W frag-packed in LDS, staged once)
// No global xg intermediate, no second launch, HBM latency hidden by scan.

#define T_STEPS 512
#define BATCH   512
#define K_IN    300
#define NG      64   // 4*HIDDEN
#define HID     16
#define CHUNK   16
#define NCHUNK  (T_STEPS / CHUNK)   // 32

typedef float  f32x4  __attribute__((ext_vector_type(4)));
typedef float  f32x8  __attribute__((ext_vector_type(8)));
typedef __bf16 bf16x8 __attribute__((ext_vector_type(8)));

static __device__ __forceinline__ bf16x8 cvt8(float4 lo, float4 hi) {
    f32x8 t;
    t[0] = lo.x; t[1] = lo.y; t[2] = lo.z; t[3] = lo.w;
    t[4] = hi.x; t[5] = hi.y; t[6] = hi.z; t[7] = hi.w;
    return __builtin_convertvector(t, bf16x8);
}

__global__ __launch_bounds__(64) void lstm_fused(
    const float* __restrict__ x,      // [T*B][300]
    const float* __restrict__ W,      // [64][300]  W_ih
    const float* __restrict__ b_ih,   // [64]
    const float* __restrict__ b_hh,   // [64]
    const float* __restrict__ Whh,    // [64][16]
    const float* __restrict__ W1,     // [64][16]
    const float* __restrict__ b1,     // [64]
    const float* __restrict__ W2,     // [64]
    const float* __restrict__ b2,     // [1]
    float* __restrict__ out)          // [B]
{
    __shared__ __align__(16) __bf16 Wl[40 * 512];   // 40 KiB frag-packed W_ih
    __shared__ float xs[NG * 17];                   // 4.25 KiB chunk pre-acts

    const int lane  = threadIdx.x;       // 0..63 = gate-row (qd*16 + j)
    const int m16   = lane & 15;         // j / MFMA row-lane
    const int quad  = lane >> 4;         // qd / MFMA k-quad
    const int batch = blockIdx.x;
    const float4 z4 = {0.f, 0.f, 0.f, 0.f};

    // ---- chunk 0 A-loads first (latency overlaps W staging)
    float4 alo[10], ahi[10];
    {
        const float* xr = x + ((size_t)m16 * BATCH + batch) * K_IN;
#pragma unroll
        for (int ks = 0; ks < 10; ++ks) {
            const int k = ks * 32 + quad * 8;
            alo[ks] = (k + 3 < K_IN) ? *(const float4*)(xr + k)     : z4;
            ahi[ks] = (k + 7 < K_IN) ? *(const float4*)(xr + k + 4) : z4;
        }
    }

    // ---- W_ih fragment staging (each lane writes & later reads its own slots)
#pragma unroll
    for (int nt = 0; nt < 4; ++nt) {
        const float* wrow = W + (size_t)(nt * 16 + m16) * K_IN;
#pragma unroll
        for (int ks = 0; ks < 10; ++ks) {
            const int k = ks * 32 + quad * 8;
            const float4 lo = (k + 3 < K_IN) ? *(const float4*)(wrow + k)     : z4;
            const float4 hi = (k + 7 < K_IN) ? *(const float4*)(wrow + k + 4) : z4;
            *(bf16x8*)&Wl[(ks * 4 + nt) * 512 + lane * 8] = cvt8(lo, hi);
        }
    }

    // ---- scan constants
    float w[HID];                         // W_hh row 'lane'
#pragma unroll
    for (int k = 0; k < HID; k += 4)
        *(float4*)&w[k] = *(const float4*)(Whh + lane * HID + k);

    // sigmoid for i/f/o, tanh for g (= 2*sig(2x)-1)
    const float kk = (quad == 2) ? -2.f : -1.f;
    const float mm = (quad == 2) ?  2.f :  1.f;
    const float nn = (quad == 2) ? -1.f :  0.f;
    const int aI = 4 * m16, aF = 4 * (16 + m16),
              aG = 4 * (32 + m16), aO = 4 * (48 + m16);

    float bias[4];
#pragma unroll
    for (int nt = 0; nt < 4; ++nt)
        bias[nt] = b_ih[nt * 16 + m16] + b_hh[nt * 16 + m16];

    float c = 0.f;
    float hs[HID];
#pragma unroll
    for (int k = 0; k < HID; ++k) hs[k] = 0.f;

    // ---- MFMA chunk 0 -> acc
    f32x4 acc[4];
#pragma unroll
    for (int nt = 0; nt < 4; ++nt) acc[nt] = (f32x4){0.f, 0.f, 0.f, 0.f};
#pragma unroll
    for (int ks = 0; ks < 10; ++ks) {
        const bf16x8 af = cvt8(alo[ks], ahi[ks]);
#pragma unroll
        for (int nt = 0; nt < 4; ++nt)
            acc[nt] = __builtin_amdgcn_mfma_f32_16x16x32_bf16(
                af, *(const bf16x8*)&Wl[(ks * 4 + nt) * 512 + lane * 8],
                acc[nt], 0, 0, 0);
    }

#pragma unroll 1
    for (int ci = 0; ci < NCHUNK; ++ci) {
        // 1. issue next chunk's x-loads (consumed at step 4; in flight all chunk)
        if (ci + 1 < NCHUNK) {
            const float* xr =
                x + ((size_t)((ci + 1) * CHUNK + m16) * BATCH + batch) * K_IN;
#pragma unroll
            for (int ks = 0; ks < 10; ++ks) {
                const int k = ks * 32 + quad * 8;
                alo[ks] = (k + 3 < K_IN) ? *(const float4*)(xr + k)     : z4;
                ahi[ks] = (k + 7 < K_IN) ? *(const float4*)(xr + k + 4) : z4;
            }
        }

        // 2. acc(ci) + bias -> xs[gate][t], pad 17 (read side conflict-free)
        //    C/D layout: lane holds acc[nt][reg] = pre[t=quad*4+reg][nt*16+m16]
#pragma unroll
        for (int nt = 0; nt < 4; ++nt)
#pragma unroll
            for (int reg = 0; reg < 4; ++reg)
                xs[(nt * 16 + m16) * 17 + quad * 4 + reg] = acc[nt][reg] + bias[nt];

        // compiler fence: cross-lane xs writes->reads (HW DS pipe is in-order)
        asm volatile("" ::: "memory");

        // 3. scan CHUNK steps
#pragma unroll
        for (int tin = 0; tin < CHUNK; ++tin) {
            const float pre = xs[lane * 17 + tin];

            float p0 = pre, p1 = 0.f, p2 = 0.f, p3 = 0.f;
#pragma unroll
            for (int k = 0; k < 4; ++k) {
                p0 = fmaf(w[k],      hs[k],      p0);
                p1 = fmaf(w[k + 4],  hs[k + 4],  p1);
                p2 = fmaf(w[k + 8],  hs[k + 8],  p2);
                p3 = fmaf(w[k + 12], hs[k + 12], p3);
            }
            const float s = (p0 + p1) + (p2 + p3);

            const float a   = __builtin_amdgcn_rcpf(1.f + __expf(kk * s));
            const float act = fmaf(a, mm, nn);

            const int av = __float_as_int(act);
            const float gi = __int_as_float(__builtin_amdgcn_ds_bpermute(aI, av));
            const float gf = __int_as_float(__builtin_amdgcn_ds_bpermute(aF, av));
            const float gg = __int_as_float(__builtin_amdgcn_ds_bpermute(aG, av));
            const float go = __int_as_float(__builtin_amdgcn_ds_bpermute(aO, av));

            c = fmaf(gf, c, gi * gg);
            const float th = fmaf(2.f, __builtin_amdgcn_rcpf(1.f + __expf(-2.f * c)), -1.f);
            const float h  = go * th;

            const int hI = __float_as_int(h);
#pragma unroll
            for (int k = 0; k < HID; ++k)
                hs[k] = __int_as_float(__builtin_amdgcn_readlane(hI, k));
        }

        // compiler fence: scan reads of xs complete before next chunk's writes
        asm volatile("" ::: "memory");

        // 4. MFMA chunk ci+1 (A-loads have had the whole scan to land)
        if (ci + 1 < NCHUNK) {
#pragma unroll
            for (int nt = 0; nt < 4; ++nt) acc[nt] = (f32x4){0.f, 0.f, 0.f, 0.f};
#pragma unroll
            for (int ks = 0; ks < 10; ++ks) {
                const bf16x8 af = cvt8(alo[ks], ahi[ks]);
#pragma unroll
                for (int nt = 0; nt < 4; ++nt)
                    acc[nt] = __builtin_amdgcn_mfma_f32_16x16x32_bf16(
                        af, *(const bf16x8*)&Wl[(ks * 4 + nt) * 512 + lane * 8],
                        acc[nt], 0, 0, 0);
            }
        }
    }

    // ---- fused MLP head: lane handles z row 'lane'
    float z = b1[lane];
#pragma unroll
    for (int k = 0; k < HID; ++k)
        z = fmaf(W1[lane * HID + k], hs[k], z);
    z = fmaxf(z, 0.f);
    float y = z * W2[lane];

#pragma unroll
    for (int m = 1; m < 64; m <<= 1) y += __shfl_xor(y, m, 64);

    if (lane == 0)
        out[batch] = 4.f * __builtin_amdgcn_rcpf(1.f + __expf(-(y + b2[0])));
}

extern "C" void kernel_launch(void* const* d_in, const int* in_sizes, int n_in,
                              void* d_out, int out_size, void* d_ws, size_t ws_size,
                              hipStream_t stream) {
    const float* x    = (const float*)d_in[0];
    const float* W_ih = (const float*)d_in[1];
    const float* W_hh = (const float*)d_in[2];
    const float* b_ih = (const float*)d_in[3];
    const float* b_hh = (const float*)d_in[4];
    const float* W1   = (const float*)d_in[5];
    const float* b1   = (const float*)d_in[6];
    const float* W2   = (const float*)d_in[7];
    const float* b2   = (const float*)d_in[8];
    float* out = (float*)d_out;
    (void)d_ws; (void)ws_size;   // workspace unused (fully fused)

    lstm_fused<<<dim3(BATCH), dim3(64), 0, stream>>>(
        x, W_ih, b_ih, b_hh, W_hh, W1, b1, W2, b2, out);
}